// Round 5
// baseline (427.896 us; speedup 1.0000x reference)
//
#include <hip/hip_runtime.h>

#define B_ 4
#define N_ 8192
#define DIN 64
#define HDIM 64
#define DOUT 128
#define KNN 16
#define QPB 64               // queries per block
#define NTHR 512             // 8 waves
#define BLOCKS_PER_B (N_ / QPB)  // 128

__device__ __forceinline__ int mbcnt64(unsigned long long m) {
  return __builtin_amdgcn_mbcnt_hi((unsigned)(m >> 32),
         __builtin_amdgcn_mbcnt_lo((unsigned)m, 0));
}
// monotone float->uint map (total order, negatives below positives)
__device__ __forceinline__ unsigned mapkey(float d) {
  unsigned u = __float_as_uint(d);
  return (d < 0.0f) ? ~u : (u | 0x80000000u);
}
__device__ __forceinline__ float rf(float x) {  // force wave-uniform into SGPR
  return __int_as_float(__builtin_amdgcn_readfirstlane(__float_as_int(x)));
}

// Wave-cooperative exact 16 smallest by (key, idx) among cnt slots (cnt<=64).
// fout==null: compact kept 16 to slots 0..15, return kth distance (unmapped).
// fout!=null: write kept idx to fout[rank*64].
__device__ __attribute__((noinline))
float select16(unsigned* skQ, unsigned short* siQ, int cnt, unsigned short* fout) {
  const int l = threadIdx.x & 63;
  unsigned k = 0xFFFFFFFFu;
  unsigned mi = 0xFFFFu;
  if (l < cnt) { k = skQ[l]; mi = siQ[l]; }
  // radix-select 16th smallest key (bitwise, MSB->LSB)
  unsigned p = 0; int r = KNN;
  for (int bit = 31; bit >= 0; bit--) {
    unsigned long long ml = __ballot((int)(((k ^ p) >> bit) == 0u));
    int c0 = __popcll(ml);
    if (r > c0) { p |= (1u << bit); r -= c0; }
  }
  bool isLT = (k < p), isTie = (k == p);
  int tieC = __popcll(__ballot((int)isTie));
  bool keepT = isTie;
  if (tieC != r) {  // break ties at the kth value by smallest index
    unsigned mk = isTie ? mi : 0xFFFFFFFFu;
    unsigned p2 = 0; int r2 = r;
    for (int bit = 15; bit >= 0; bit--) {
      unsigned long long ml = __ballot((int)(((mk ^ p2) >> bit) == 0u));
      int c0 = __popcll(ml);
      if (r2 > c0) { p2 |= (1u << bit); r2 -= c0; }
    }
    keepT = isTie && (mi <= p2);
  }
  bool keep = isLT || keepT;
  unsigned long long km = __ballot((int)keep);
  int rank = mbcnt64(km);
  if (fout) {
    if (keep) fout[rank * QPB] = (unsigned short)mi;
  } else {
    if (keep) { skQ[rank] = k; siQ[rank] = (unsigned short)mi; }
  }
  unsigned fb = (p & 0x80000000u) ? (p & 0x7FFFFFFFu) : ~p;  // unmap
  return __uint_as_float(fb);
}

// ---------------- fully fused kernel ----------------
// Phase 0: compose 3 affine layers -> prmL (A,B,C,D per channel)
// Phase 1: transposed kNN scan: wave j owns queries n0+j*8..+7; lanes = candidates.
//          Per-query 64-slot survivor buffer + exact radix-select compaction.
// Phase 2: final selection -> fidx; gather neighbors; fe = affine+maxpool;
//          shortcut GEMM from LDS; store.
__global__ __launch_bounds__(NTHR, 6) void k_lfa(
    const float* __restrict__ xyz, const float* __restrict__ feature,
    const float* __restrict__ w1, const float* __restrict__ b1,
    const float* __restrict__ w2, const float* __restrict__ b2,
    const float* __restrict__ w3, const float* __restrict__ b3,
    const float* __restrict__ wsM, const float* __restrict__ bs,
    float* __restrict__ out) {
  const int blk = blockIdx.x;
  const int b  = blk / BLOCKS_PER_B;
  const int n0 = (blk % BLOCKS_PER_B) * QPB;
  const int t = threadIdx.x;
  const int lane = t & 63;
  const int j = __builtin_amdgcn_readfirstlane(t >> 6);
  const float* xb = xyz + (size_t)b * 3 * N_;
  const float INF = __uint_as_float(0x7f800000u);

  // 48 KB pool, time-multiplexed:
  //  phase0: M2[64][10] @0, bb @2560
  //  scan:   skey[64][64] @0 (16K), sidx[64][64] @16384 (8K),
  //          fidx[16][64] @24576 (2K), prmL[128]f4 @26624 (2K)
  //  epi:    neighbor rows [64][64] @0 (16K) -> then wsL[128][64] @0 (32K),
  //          feL[64][64] @32768 (16K)
  __shared__ alignas(16) unsigned char poolRaw[49152];
  unsigned* skey = (unsigned*)poolRaw;
  unsigned short* sidx = (unsigned short*)(poolRaw + 16384);
  unsigned short* fidx = (unsigned short*)(poolRaw + 24576);
  float4* prmL = (float4*)(poolRaw + 26624);

  // ---- phase 0: affine composition (threads < 64) ----
  {
    float* M2 = (float*)poolRaw;             // [64][10]
    float* bbv = (float*)(poolRaw + 2560);   // [64]
    if (t < HDIM) {
      float r[10];
#pragma unroll
      for (int c = 0; c < 10; c++) r[c] = 0.f;
      float s = b2[t];
      for (int ll = 0; ll < HDIM; ll++) {
        float w = w2[t * HDIM + ll];
#pragma unroll
        for (int c = 0; c < 10; c++) r[c] = fmaf(w, w1[ll * 10 + c], r[c]);
        s = fmaf(w, b1[ll], s);
      }
#pragma unroll
      for (int c = 0; c < 10; c++) M2[t * 10 + c] = r[c];
      bbv[t] = s;
    }
    __syncthreads();
    if (t < HDIM) {
      float r3[10];
#pragma unroll
      for (int c = 0; c < 10; c++) r3[c] = 0.f;
      float bc = b3[t];
      for (int ll = 0; ll < HDIM; ll++) {
        float w = w3[t * HDIM + ll];
#pragma unroll
        for (int c = 0; c < 10; c++) r3[c] = fmaf(w, M2[ll * 10 + c], r3[c]);
        bc = fmaf(w, bbv[ll], bc);
      }
      prmL[t]      = make_float4(r3[0] - r3[6], r3[1] - r3[7], r3[2] - r3[8], bc);
      prmL[64 + t] = make_float4(r3[3] + r3[6], r3[4] + r3[7], r3[5] + r3[8], r3[9]);
    }
    __syncthreads();
  }

  // ---- phase 1: scan ----
  float qX[8], qY[8], qZ[8], qS[8];
#pragma unroll
  for (int i = 0; i < 8; i++) {
    int mq = n0 + j * 8 + i;
    float x = xb[mq], y = xb[N_ + mq], z = xb[2 * N_ + mq];
    float sq = __fadd_rn(__fadd_rn(__fmul_rn(x, x), __fmul_rn(y, y)), __fmul_rn(z, z));
    qX[i] = rf(x); qY[i] = rf(y); qZ[i] = rf(z); qS[i] = rf(sq);
  }
  float tauF[8]; int cntA[8];
#pragma unroll
  for (int i = 0; i < 8; i++) { tauF[i] = INF; cntA[i] = 0; }

  float cx = xb[lane], cy = xb[N_ + lane], cz = xb[2 * N_ + lane];
  for (int m0 = 0; m0 < N_; m0 += 64) {
    int mn = (m0 + 64) & (N_ - 1);  // wrapped prefetch (always in-bounds)
    float px = xb[mn + lane], py = xb[N_ + mn + lane], pz = xb[2 * N_ + mn + lane];
    float cw = __fadd_rn(__fadd_rn(__fmul_rn(cx, cx), __fmul_rn(cy, cy)),
                         __fmul_rn(cz, cz));
    float dd[8];
#pragma unroll
    for (int i = 0; i < 8; i++) {  // reference rounding: fma-chain dot, mul/add sums
      float dot = fmaf(cz, qZ[i], fmaf(cy, qY[i], __fmul_rn(cx, qX[i])));
      dd[i] = __fsub_rn(__fadd_rn(qS[i], cw), __fmul_rn(2.0f, dot));
    }
#pragma unroll
    for (int i = 0; i < 8; i++) {
      unsigned long long hit = __ballot((int)(dd[i] < tauF[i]));
      if (hit) {
        unsigned* skQ = skey + (j * 8 + i) * QPB;
        unsigned short* siQ = sidx + (j * 8 + i) * QPB;
        bool mine = dd[i] < tauF[i];
        int h = __popcll(hit);
        int rk = mbcnt64(hit);
        unsigned key = mapkey(dd[i]);
        unsigned short mm = (unsigned short)(m0 + lane);
        if (cntA[i] + h <= QPB) {  // fast path
          if (mine) { skQ[cntA[i] + rk] = key; siQ[cntA[i] + rk] = mm; }
          cntA[i] += h;
          if (cntA[i] == QPB) {
            tauF[i] = rf(select16(skQ, siQ, QPB, nullptr));
            cntA[i] = KNN;
          }
        } else {  // overflow: write in rounds, compacting as needed
          unsigned long long rem = hit; bool mrem = mine;
          while (rem) {
            int freeS = QPB - cntA[i];
            int hh = __popcll(rem);
            int rr = mbcnt64(rem);
            bool wn = mrem && (rr < freeS);
            if (wn) { skQ[cntA[i] + rr] = key; siQ[cntA[i] + rr] = mm; }
            cntA[i] += (hh < freeS) ? hh : freeS;
            if (cntA[i] == QPB) {
              tauF[i] = rf(select16(skQ, siQ, QPB, nullptr));
              cntA[i] = KNN;
            }
            mrem = mrem && !wn && (dd[i] < tauF[i]);
            rem = __ballot((int)mrem);
          }
        }
      }
    }
    cx = px; cy = py; cz = pz;
  }
  // final exact selection per query -> fidx[slot][query]
#pragma unroll
  for (int i = 0; i < 8; i++) {
    select16(skey + (j * 8 + i) * QPB, sidx + (j * 8 + i) * QPB,
             cntA[i], fidx + (j * 8 + i));
  }
  __syncthreads();

  // ---- phase 2: epilogue (lane = query) ----
  const int q = lane;
  float qx = xb[n0 + q], qy = xb[N_ + n0 + q], qz = xb[2 * N_ + n0 + q];
  float* poolF = (float*)poolRaw;  // neighbor rows [64][64] (overwrites skey)
#pragma unroll
  for (int kk = 0; kk < 2; kk++) {
    int k = j * 2 + kk;
    int m = fidx[k * QPB + q];
    float x = xb[m], y = xb[N_ + m], z = xb[2 * N_ + m];
    float dx = __fsub_rn(x, qx), dy = __fsub_rn(y, qy), dz = __fsub_rn(z, qz);
    float dsq = __fadd_rn(__fadd_rn(__fmul_rn(dx, dx), __fmul_rn(dy, dy)),
                          __fmul_rn(dz, dz));
    poolF[k * QPB + q] = x;
    poolF[(KNN + k) * QPB + q] = y;
    poolF[(2 * KNN + k) * QPB + q] = z;
    poolF[(3 * KNN + k) * QPB + q] = dsq;
  }
  __syncthreads();

  float fo[8];
  {
    float nx[KNN], ny[KNN], nz[KNN], nd[KNN];
#pragma unroll
    for (int k = 0; k < KNN; k++) {
      nx[k] = poolF[k * QPB + q];
      ny[k] = poolF[(KNN + k) * QPB + q];
      nz[k] = poolF[(2 * KNN + k) * QPB + q];
      nd[k] = poolF[(3 * KNN + k) * QPB + q];
    }
#pragma unroll
    for (int oi = 0; oi < 8; oi++) {
      int o = j * 8 + oi;
      float4 pA = prmL[o], pB = prmL[HDIM + o];
      float basev = fmaf(qz, pA.z, fmaf(qy, pA.y, fmaf(qx, pA.x, pA.w)));
      float mx = -INF;
#pragma unroll
      for (int k = 0; k < KNN; k++) {
        float tv = fmaf(nz[k], pB.z,
                   fmaf(ny[k], pB.y,
                   fmaf(nx[k], pB.x, __fmul_rn(nd[k], pB.w))));
        mx = fmaxf(mx, tv);
      }
      fo[oi] = basev + mx;
    }
  }
  __syncthreads();  // pool free (prmL/fidx dead from here)

  float* wsL = (float*)poolRaw;              // [128][64] 32 KB
  float* feL = (float*)(poolRaw + 32768);    // [64][64] 16 KB
  for (int i2 = t; i2 < DOUT * DIN; i2 += NTHR) wsL[i2] = wsM[i2];
#pragma unroll
  for (int r = 0; r < 8; r++) {
    int c = j * 8 + r;
    feL[c * QPB + q] = feature[(size_t)(b * DIN + c) * N_ + n0 + q];
  }
  __syncthreads();

  float acc[16];
#pragma unroll
  for (int oi = 0; oi < 16; oi++) acc[oi] = 0.f;
  for (int c4 = 0; c4 < DIN / 4; c4++) {
    float f0 = feL[(4 * c4 + 0) * QPB + q];
    float f1 = feL[(4 * c4 + 1) * QPB + q];
    float f2 = feL[(4 * c4 + 2) * QPB + q];
    float f3 = feL[(4 * c4 + 3) * QPB + q];
#pragma unroll
    for (int oi = 0; oi < 16; oi++) {
      int o = (oi < 8) ? (j * 8 + oi) : (64 + j * 8 + oi - 8);
      float4 w = ((const float4*)(wsL + o * DIN))[c4];  // wave-uniform broadcast
      acc[oi] = fmaf(w.x, f0, acc[oi]);
      acc[oi] = fmaf(w.y, f1, acc[oi]);
      acc[oi] = fmaf(w.z, f2, acc[oi]);
      acc[oi] = fmaf(w.w, f3, acc[oi]);
    }
  }
  float* ob = out + (size_t)b * DOUT * N_ + n0 + q;
#pragma unroll
  for (int oi = 0; oi < 16; oi++) {
    int o = (oi < 8) ? (j * 8 + oi) : (64 + j * 8 + oi - 8);
    ob[(size_t)o * N_] = acc[oi] + bs[o] + fo[oi & 7];
  }
}

extern "C" void kernel_launch(void* const* d_in, const int* in_sizes, int n_in,
                              void* d_out, int out_size, void* d_ws, size_t ws_size,
                              hipStream_t stream) {
  const float* xyz     = (const float*)d_in[0];
  const float* feature = (const float*)d_in[1];
  const float* w1 = (const float*)d_in[2];
  const float* b1 = (const float*)d_in[3];
  const float* w2 = (const float*)d_in[4];
  const float* b2 = (const float*)d_in[5];
  const float* w3 = (const float*)d_in[6];
  const float* b3 = (const float*)d_in[7];
  const float* wsM = (const float*)d_in[8];
  const float* bs  = (const float*)d_in[9];
  float* out = (float*)d_out;

  hipLaunchKernelGGL(k_lfa, dim3(B_ * BLOCKS_PER_B), dim3(NTHR), 0, stream,
                     xyz, feature, w1, b1, w2, b2, w3, b3, wsM, bs, out);
}

// Round 6
// 291.904 us; speedup vs baseline: 1.4659x; 1.4659x over previous
//
#include <hip/hip_runtime.h>

#define B_ 4
#define N_ 8192
#define DIN 64
#define HDIM 64
#define DOUT 128
#define KNN 16
#define QPB 64               // queries per block
#define NTHR 512             // 8 waves
#define BLOCKS_PER_B (N_ / QPB)  // 128

__device__ __forceinline__ int mbcnt64(unsigned long long m) {
  return __builtin_amdgcn_mbcnt_hi((unsigned)(m >> 32),
         __builtin_amdgcn_mbcnt_lo((unsigned)m, 0));
}
// monotone float->uint map (total order, negatives below positives)
__device__ __forceinline__ unsigned mapkey(float d) {
  unsigned u = __float_as_uint(d);
  return (d < 0.0f) ? ~u : (u | 0x80000000u);
}
__device__ __forceinline__ float rf(float x) {  // force wave-uniform into SGPR
  return __int_as_float(__builtin_amdgcn_readfirstlane(__float_as_int(x)));
}

// Wave-cooperative exact 16 smallest by (key, idx) among cnt slots (cnt<=64).
// fout==null: compact kept 16 to slots 0..15, return kth distance (unmapped).
// fout!=null: write kept idx to fout[rank*64].
__device__ __forceinline__
float select16(unsigned* skQ, unsigned short* siQ, int cnt, unsigned short* fout) {
  const int l = threadIdx.x & 63;
  unsigned k = 0xFFFFFFFFu;
  unsigned mi = 0xFFFFu;
  if (l < cnt) { k = skQ[l]; mi = siQ[l]; }
  // radix-select 16th smallest key (bitwise, MSB->LSB)
  unsigned p = 0; int r = KNN;
  for (int bit = 31; bit >= 0; bit--) {
    unsigned long long ml = __ballot((int)(((k ^ p) >> bit) == 0u));
    int c0 = __popcll(ml);
    if (r > c0) { p |= (1u << bit); r -= c0; }
  }
  bool isLT = (k < p), isTie = (k == p);
  int tieC = __popcll(__ballot((int)isTie));
  bool keepT = isTie;
  if (tieC != r) {  // break ties at the kth value by smallest index
    unsigned mk = isTie ? mi : 0xFFFFFFFFu;
    unsigned p2 = 0; int r2 = r;
    for (int bit = 15; bit >= 0; bit--) {
      unsigned long long ml = __ballot((int)(((mk ^ p2) >> bit) == 0u));
      int c0 = __popcll(ml);
      if (r2 > c0) { p2 |= (1u << bit); r2 -= c0; }
    }
    keepT = isTie && (mi <= p2);
  }
  bool keep = isLT || keepT;
  unsigned long long km = __ballot((int)keep);
  int rank = mbcnt64(km);
  if (fout) {
    if (keep) fout[rank * QPB] = (unsigned short)mi;
  } else {
    if (keep) { skQ[rank] = k; siQ[rank] = (unsigned short)mi; }
  }
  unsigned fb = (p & 0x80000000u) ? (p & 0x7FFFFFFFu) : ~p;  // unmap
  return __uint_as_float(fb);
}

// ---------------- fully fused kernel ----------------
// Phase 0: compose 3 affine layers -> prmL (A,B,C,D per channel)
// Phase 1: transposed kNN scan: wave j owns queries n0+j*8..+7; lanes = candidates.
//          128 candidates/iter, loads one iteration ahead. Survivors go to a
//          per-query 64-slot LDS buffer; exact radix-select compaction sets tau.
// Phase 2: final selection -> fidx; gather neighbors; fe = affine+maxpool;
//          shortcut GEMM from LDS; store.
__global__ __launch_bounds__(NTHR, 4) void k_lfa(
    const float* __restrict__ xyz, const float* __restrict__ feature,
    const float* __restrict__ w1, const float* __restrict__ b1,
    const float* __restrict__ w2, const float* __restrict__ b2,
    const float* __restrict__ w3, const float* __restrict__ b3,
    const float* __restrict__ wsM, const float* __restrict__ bs,
    float* __restrict__ out) {
  const int blk = blockIdx.x;
  const int b  = blk / BLOCKS_PER_B;
  const int n0 = (blk % BLOCKS_PER_B) * QPB;
  const int t = threadIdx.x;
  const int lane = t & 63;
  const int j = __builtin_amdgcn_readfirstlane(t >> 6);
  const float* xb = xyz + (size_t)b * 3 * N_;
  const float INF = __uint_as_float(0x7f800000u);

  // 48 KB pool, time-multiplexed:
  //  phase0: M2[64][10] @0, bb @2560
  //  scan:   skey[64][64] @0 (16K), sidx[64][64] @16384 (8K),
  //          fidx[16][64] @24576 (2K), prmL[128]f4 @26624 (2K)
  //  epi:    neighbor rows [64][64] @0 (16K) -> then wsL[128][64] @0 (32K),
  //          feL[64][64] @32768 (16K)
  __shared__ alignas(16) unsigned char poolRaw[49152];
  unsigned* skey = (unsigned*)poolRaw;
  unsigned short* sidx = (unsigned short*)(poolRaw + 16384);
  unsigned short* fidx = (unsigned short*)(poolRaw + 24576);
  float4* prmL = (float4*)(poolRaw + 26624);

  // ---- phase 0: affine composition (threads < 64) ----
  {
    float* M2 = (float*)poolRaw;             // [64][10]
    float* bbv = (float*)(poolRaw + 2560);   // [64]
    if (t < HDIM) {
      float r[10];
#pragma unroll
      for (int c = 0; c < 10; c++) r[c] = 0.f;
      float s = b2[t];
      for (int ll = 0; ll < HDIM; ll++) {
        float w = w2[t * HDIM + ll];
#pragma unroll
        for (int c = 0; c < 10; c++) r[c] = fmaf(w, w1[ll * 10 + c], r[c]);
        s = fmaf(w, b1[ll], s);
      }
#pragma unroll
      for (int c = 0; c < 10; c++) M2[t * 10 + c] = r[c];
      bbv[t] = s;
    }
    __syncthreads();
    if (t < HDIM) {
      float r3[10];
#pragma unroll
      for (int c = 0; c < 10; c++) r3[c] = 0.f;
      float bc = b3[t];
      for (int ll = 0; ll < HDIM; ll++) {
        float w = w3[t * HDIM + ll];
#pragma unroll
        for (int c = 0; c < 10; c++) r3[c] = fmaf(w, M2[ll * 10 + c], r3[c]);
        bc = fmaf(w, bbv[ll], bc);
      }
      prmL[t]      = make_float4(r3[0] - r3[6], r3[1] - r3[7], r3[2] - r3[8], bc);
      prmL[64 + t] = make_float4(r3[3] + r3[6], r3[4] + r3[7], r3[5] + r3[8], r3[9]);
    }
    __syncthreads();
  }

  // ---- phase 1: scan ----
  float qX[8], qY[8], qZ[8], qS[8];
#pragma unroll
  for (int i = 0; i < 8; i++) {
    int mq = n0 + j * 8 + i;
    float x = xb[mq], y = xb[N_ + mq], z = xb[2 * N_ + mq];
    float sq = __fadd_rn(__fadd_rn(__fmul_rn(x, x), __fmul_rn(y, y)), __fmul_rn(z, z));
    qX[i] = rf(x); qY[i] = rf(y); qZ[i] = rf(z); qS[i] = rf(sq);
  }
  float tauF[8]; int cntA[8];
#pragma unroll
  for (int i = 0; i < 8; i++) { tauF[i] = INF; cntA[i] = 0; }

  auto pushBatch = [&](float cx, float cy, float cz, int base) {
    float cw = __fadd_rn(__fadd_rn(__fmul_rn(cx, cx), __fmul_rn(cy, cy)),
                         __fmul_rn(cz, cz));
    float dd[8];
#pragma unroll
    for (int i = 0; i < 8; i++) {  // reference rounding: fma-chain dot, mul/add sums
      float dot = fmaf(cz, qZ[i], fmaf(cy, qY[i], __fmul_rn(cx, qX[i])));
      dd[i] = __fsub_rn(__fadd_rn(qS[i], cw), __fmul_rn(2.0f, dot));
    }
#pragma unroll
    for (int i = 0; i < 8; i++) {
      bool mine = dd[i] < tauF[i];
      unsigned long long hit = __ballot((int)mine);
      if (hit) {
        unsigned* skQ = skey + (j * 8 + i) * QPB;
        unsigned short* siQ = sidx + (j * 8 + i) * QPB;
        int h = __popcll(hit);
        int rk = mbcnt64(hit);
        unsigned key = mapkey(dd[i]);
        unsigned short mm = (unsigned short)(base + lane);
        if (cntA[i] + h <= QPB) {  // fast path
          if (mine) { skQ[cntA[i] + rk] = key; siQ[cntA[i] + rk] = mm; }
          cntA[i] += h;
          if (cntA[i] == QPB) {
            tauF[i] = rf(select16(skQ, siQ, QPB, nullptr));
            cntA[i] = KNN;
          }
        } else {  // overflow: write in rounds, compacting as needed
          unsigned long long rem = hit; bool mrem = mine;
          while (rem) {
            int freeS = QPB - cntA[i];
            int hh = __popcll(rem);
            int rr = mbcnt64(rem);
            bool wn = mrem && (rr < freeS);
            if (wn) { skQ[cntA[i] + rr] = key; siQ[cntA[i] + rr] = mm; }
            cntA[i] += (hh < freeS) ? hh : freeS;
            if (cntA[i] == QPB) {
              tauF[i] = rf(select16(skQ, siQ, QPB, nullptr));
              cntA[i] = KNN;
            }
            mrem = mrem && !wn && (dd[i] < tauF[i]);
            rem = __ballot((int)mrem);
          }
        }
      }
    }
  };

  // software pipeline: load 128 candidates one iteration ahead
  float ax = xb[lane],      ay = xb[N_ + lane],      az = xb[2 * N_ + lane];
  float bx = xb[64 + lane], by = xb[N_ + 64 + lane], bz = xb[2 * N_ + 64 + lane];
  for (int m0 = 0; m0 < N_; m0 += 128) {
    const int mn = (m0 + 128) & (N_ - 1);  // wrapped prefetch (always in-bounds)
    float nax = xb[mn + lane],      nay = xb[N_ + mn + lane],
          naz = xb[2 * N_ + mn + lane];
    float nbx = xb[mn + 64 + lane], nby = xb[N_ + mn + 64 + lane],
          nbz = xb[2 * N_ + mn + 64 + lane];
    pushBatch(ax, ay, az, m0);
    pushBatch(bx, by, bz, m0 + 64);
    ax = nax; ay = nay; az = naz;
    bx = nbx; by = nby; bz = nbz;
  }
  // final exact selection per query -> fidx[slot][query]
#pragma unroll
  for (int i = 0; i < 8; i++) {
    select16(skey + (j * 8 + i) * QPB, sidx + (j * 8 + i) * QPB,
             cntA[i], fidx + (j * 8 + i));
  }
  __syncthreads();

  // ---- phase 2: epilogue (lane = query) ----
  const int q = lane;
  float qx = xb[n0 + q], qy = xb[N_ + n0 + q], qz = xb[2 * N_ + n0 + q];
  float* poolF = (float*)poolRaw;  // neighbor rows [64][64] (overwrites skey)
#pragma unroll
  for (int kk = 0; kk < 2; kk++) {
    int k = j * 2 + kk;
    int m = fidx[k * QPB + q];
    float x = xb[m], y = xb[N_ + m], z = xb[2 * N_ + m];
    float dx = __fsub_rn(x, qx), dy = __fsub_rn(y, qy), dz = __fsub_rn(z, qz);
    float dsq = __fadd_rn(__fadd_rn(__fmul_rn(dx, dx), __fmul_rn(dy, dy)),
                          __fmul_rn(dz, dz));
    poolF[k * QPB + q] = x;
    poolF[(KNN + k) * QPB + q] = y;
    poolF[(2 * KNN + k) * QPB + q] = z;
    poolF[(3 * KNN + k) * QPB + q] = dsq;
  }
  __syncthreads();

  float fo[8];
  {
    float nx[KNN], ny[KNN], nz[KNN], nd[KNN];
#pragma unroll
    for (int k = 0; k < KNN; k++) {
      nx[k] = poolF[k * QPB + q];
      ny[k] = poolF[(KNN + k) * QPB + q];
      nz[k] = poolF[(2 * KNN + k) * QPB + q];
      nd[k] = poolF[(3 * KNN + k) * QPB + q];
    }
#pragma unroll
    for (int oi = 0; oi < 8; oi++) {
      int o = j * 8 + oi;
      float4 pA = prmL[o], pB = prmL[HDIM + o];
      float basev = fmaf(qz, pA.z, fmaf(qy, pA.y, fmaf(qx, pA.x, pA.w)));
      float mx = -INF;
#pragma unroll
      for (int k = 0; k < KNN; k++) {
        float tv = fmaf(nz[k], pB.z,
                   fmaf(ny[k], pB.y,
                   fmaf(nx[k], pB.x, __fmul_rn(nd[k], pB.w))));
        mx = fmaxf(mx, tv);
      }
      fo[oi] = basev + mx;
    }
  }
  __syncthreads();  // pool free (prmL/fidx dead from here)

  float* wsL = (float*)poolRaw;              // [128][64] 32 KB
  float* feL = (float*)(poolRaw + 32768);    // [64][64] 16 KB
  for (int i2 = t; i2 < DOUT * DIN; i2 += NTHR) wsL[i2] = wsM[i2];
#pragma unroll
  for (int r = 0; r < 8; r++) {
    int c = j * 8 + r;
    feL[c * QPB + q] = feature[(size_t)(b * DIN + c) * N_ + n0 + q];
  }
  __syncthreads();

  float acc[16];
#pragma unroll
  for (int oi = 0; oi < 16; oi++) acc[oi] = 0.f;
  for (int c4 = 0; c4 < DIN / 4; c4++) {
    float f0 = feL[(4 * c4 + 0) * QPB + q];
    float f1 = feL[(4 * c4 + 1) * QPB + q];
    float f2 = feL[(4 * c4 + 2) * QPB + q];
    float f3 = feL[(4 * c4 + 3) * QPB + q];
#pragma unroll
    for (int oi = 0; oi < 16; oi++) {
      int o = (oi < 8) ? (j * 8 + oi) : (64 + j * 8 + oi - 8);
      float4 w = ((const float4*)(wsL + o * DIN))[c4];  // wave-uniform broadcast
      acc[oi] = fmaf(w.x, f0, acc[oi]);
      acc[oi] = fmaf(w.y, f1, acc[oi]);
      acc[oi] = fmaf(w.z, f2, acc[oi]);
      acc[oi] = fmaf(w.w, f3, acc[oi]);
    }
  }
  float* ob = out + (size_t)b * DOUT * N_ + n0 + q;
#pragma unroll
  for (int oi = 0; oi < 16; oi++) {
    int o = (oi < 8) ? (j * 8 + oi) : (64 + j * 8 + oi - 8);
    ob[(size_t)o * N_] = acc[oi] + bs[o] + fo[oi & 7];
  }
}

extern "C" void kernel_launch(void* const* d_in, const int* in_sizes, int n_in,
                              void* d_out, int out_size, void* d_ws, size_t ws_size,
                              hipStream_t stream) {
  const float* xyz     = (const float*)d_in[0];
  const float* feature = (const float*)d_in[1];
  const float* w1 = (const float*)d_in[2];
  const float* b1 = (const float*)d_in[3];
  const float* w2 = (const float*)d_in[4];
  const float* b2 = (const float*)d_in[5];
  const float* w3 = (const float*)d_in[6];
  const float* b3 = (const float*)d_in[7];
  const float* wsM = (const float*)d_in[8];
  const float* bs  = (const float*)d_in[9];
  float* out = (float*)d_out;

  hipLaunchKernelGGL(k_lfa, dim3(B_ * BLOCKS_PER_B), dim3(NTHR), 0, stream,
                     xyz, feature, w1, b1, w2, b2, w3, b3, wsM, bs, out);
}